// Round 7
// baseline (771.375 us; speedup 1.0000x reference)
//
#include <hip/hip_runtime.h>

// AttentionBasedNN: persistent mega-kernel, round-11.
// VEC=1280, HID=128, B=4, S=256, fp32 (no fp32 MFMA on CDNA4 -> vector ALU).
//
// Coherence scheme (proven rounds 6-10): intermediates are WRITE-ONCE
// versioned buffers; stores bypass L1/L2 (sc0 sc1 -> coherence point),
// loads normal cached; grid barrier = fence-free monotonic tree counters.
//
// Round-10 post-mortem: scores+PV+LN fusion destroyed PV arithmetic
// intensity (each block streamed 1.31MB of Xin for 2 rows, scalar loads)
// -> 565us. REVERTED to round-9 phase structure (430us proven).
// Round-11 levers (each independently motivated by counters):
//  (1) 3 blocks/CU: grid 768, launch_bounds(256,4) (VGPR cap 128 = r9's
//      measured use -> HW capacity 4/CU > 3 needed: 256 slots slack, no
//      r8-style exact-fit deadlock). LDS: single 8.7KB shared ARENA
//      (compiler was SUMMING per-task __shared__ to 41KB -> cap 3/CU).
//      More resident waves hide the in-phase L3 latency everywhere.
//  (2) Dense-H: hsum phase materializes H = relu(sum Hp + b1) once
//      (same summation order, bit-identical); FC2 becomes a plain
//      2-deep-prefetch GEMM (kills 8x A-load amplification, ~76MB/layer).

#define DEV __device__ __forceinline__

static constexpr int VEC = 1280;
static constexpr int HID = 128;
static constexpr int BB  = 4;
static constexpr int SS  = 256;
static constexpr int NPART = 8;           // split-K partials (QK and FC1)
static constexpr long QK_PS = 262144;     // QK partial stride (1024*256)
static constexpr long H_PS  = 131072;     // FC1 partial stride (1024*128)
static constexpr int NBLK  = 768;         // persistent grid: 3 blocks/CU
static constexpr int NGRP  = 12;          // barrier groups of 64
static constexpr int NSPLIT_NONE = 1 << 30;
static constexpr int ARENA_F = 2176;      // shared arena floats (= gemm need)

typedef float f32x4 __attribute__((ext_vector_type(4)));

struct Params {
  const float* X; const int* lys;
  const float* Wq[4]; const float* Wk[4]; const float* wv[4];
  const float* rW1[3]; const float* rb1[3]; const float* rW2[3]; const float* rb2[3];
  const float* hW1; const float* hb1; const float* hW2; const float* hb2;
  const float* hW3; const float* hb3;
  float* QKp[4]; float* Qd[4]; float* KT[4];   // per attention layer
  float* attn[3]; float* Yraw[3]; float* Yb[3];
  float* Hp[3]; float* Hd[3]; float* Xout[3];
  float* out;
  // bar layout (u32): [g*32] 12 group arrive ctrs; [512] root;
  // [544+g*32] 12 per-group gen words. Cleared to 1024.
  unsigned* bar;
};

// ---- bypass stores (agent-scope, straight to coherence point) -------------
DEV void stcc(float* p, float v) {
  union { float f; unsigned u; } c; c.f = v;
  __hip_atomic_store((unsigned*)p, c.u, __ATOMIC_RELAXED,
                     __HIP_MEMORY_SCOPE_AGENT);
}
DEV void stcc4(float* p, float x, float y, float z, float w) {
  f32x4 v; v[0] = x; v[1] = y; v[2] = z; v[3] = w;
  asm volatile("global_store_dwordx4 %0, %1, off sc0 sc1"
               :: "v"(p), "v"(v) : "memory");
}

DEV float ftanh(float x) {
  float e = __expf(2.0f * x);
  return 1.0f - __fdividef(2.0f, e + 1.0f);
}

DEV float waveSum(float v) {
#pragma unroll
  for (int off = 32; off > 0; off >>= 1) v += __shfl_xor(v, off, 64);
  return v;
}
DEV float waveMax(float v) {
#pragma unroll
  for (int off = 32; off > 0; off >>= 1) v = fmaxf(v, __shfl_xor(v, off, 64));
  return v;
}
// blockDim.x == 256 (4 waves) everywhere these are used.
DEV float blockSum(float v, float* red) {
  v = waveSum(v);
  int tid = threadIdx.x;
  if ((tid & 63) == 0) red[tid >> 6] = v;
  __syncthreads();
  float r = (red[0] + red[1]) + (red[2] + red[3]);
  __syncthreads();
  return r;
}
DEV float blockMax(float v, float* red) {
  v = waveMax(v);
  int tid = threadIdx.x;
  if ((tid & 63) == 0) red[tid >> 6] = v;
  __syncthreads();
  float r = fmaxf(fmaxf(red[0], red[1]), fmaxf(red[2], red[3]));
  __syncthreads();
  return r;
}

// Fence-free grid barrier. Arrive: 12 group ctrs -> root. Release: root
// finisher broadcasts to 12 per-group gen words (64 pollers each).
DEV void gsync(unsigned* bar, unsigned target) {
  __syncthreads();  // each wave drains its own vmcnt before s_barrier
  if (threadIdx.x == 0) {
    asm volatile("s_waitcnt vmcnt(0)" ::: "memory");
    const int g = (int)(blockIdx.x >> 6);
    unsigned* grp  = bar + (g << 5);
    unsigned* root = bar + 512;
    unsigned c = __hip_atomic_fetch_add(grp, 1u, __ATOMIC_RELAXED,
                                        __HIP_MEMORY_SCOPE_AGENT);
    if (c + 1u == target * 64u) {
      unsigned r = __hip_atomic_fetch_add(root, 1u, __ATOMIC_RELAXED,
                                          __HIP_MEMORY_SCOPE_AGENT);
      if (r + 1u == target * (unsigned)NGRP) {
#pragma unroll
        for (int i = 0; i < NGRP; ++i)
          __hip_atomic_store(bar + 544 + (i << 5), target, __ATOMIC_RELAXED,
                             __HIP_MEMORY_SCOPE_AGENT);
      }
    }
    unsigned* gen = bar + 544 + (g << 5);
    while (__hip_atomic_load(gen, __ATOMIC_RELAXED,
                             __HIP_MEMORY_SCOPE_AGENT) < target)
      __builtin_amdgcn_s_sleep(2);
  }
  __syncthreads();
}

// ---------------------------------------------------------------------------
// fp32 GEMM task, 64x64 tile, BK=16, 256 threads, 4x4 microtile, 2-deep
// ping-pong register prefetch (round-9 proven; FMA order unchanged).
// Shared arena: As = smem[0..1087] as [16][68], Bs = smem[1088..2175].
// MODE==0: plain.  MODE==1: z = K-split slice (kChunk each), C += z*sCb.
// MODE==2: z = batch; A += z*sAb, B += z*sBb, C/res += z*sCb.
// Loads cached (write-once buffers); C-stores bypass 16B.
// ---------------------------------------------------------------------------
template <int MODE, bool OBIAS, bool ORES>
DEV void gemm_task(float* smem, int n0, int m0, int z,
                   const float* __restrict__ A, long sAb,
                   const float* __restrict__ B0, const float* __restrict__ B1,
                   int nSplitB, long sBb, int ldB,
                   float* __restrict__ C, long sCb,
                   const float* __restrict__ oBias,
                   const float* __restrict__ res,
                   int N, int K, int kChunk) {
  float (*As)[68] = (float (*)[68])smem;
  float (*Bs)[68] = (float (*)[68])(smem + 1088);

  const float* Ab = A + (MODE == 2 ? (long)z * sAb : 0L);
  float*       Cb = C + (MODE >= 1 ? (long)z * sCb : 0L);
  const float* resz = ORES ? (res + (MODE == 2 ? (long)z * sCb : 0L)) : nullptr;
  const float* Bsel;
  int nb;
  if (n0 < nSplitB) { Bsel = B0; nb = n0; } else { Bsel = B1; nb = n0 - nSplitB; }
  if (MODE == 2) Bsel += (long)z * sBb;

  const int kBeg = (MODE == 1) ? z * kChunk : 0;
  const int kEnd = (MODE == 1) ? kBeg + kChunk : K;

  const int tid = threadIdx.x;
  const int tx = tid & 15, ty = tid >> 4;
  const int ar = tid >> 2, ac = (tid & 3) << 2;   // A: row 0..63, k {0,4,8,12}
  const int br = tid >> 4, bc = (tid & 15) << 2;  // B: k-row 0..15, col 0..60

  auto loadA = [&](int kt) -> float4 {
    return *(const float4*)(Ab + (size_t)(m0 + ar) * K + kt + ac);
  };
  auto loadB = [&](int kt) -> float4 {
    return *(const float4*)(Bsel + (size_t)(kt + br) * ldB + nb + bc);
  };
  auto stAB = [&](const float4& a4, const float4& b4) {
    As[ac + 0][ar] = a4.x;
    As[ac + 1][ar] = a4.y;
    As[ac + 2][ar] = a4.z;
    As[ac + 3][ar] = a4.w;
    *(float4*)&Bs[br][bc] = b4;
  };

  float acc[4][4] = {};
  auto domath = [&]() {
#pragma unroll
    for (int kk = 0; kk < 16; ++kk) {
      const float4 av = *(const float4*)&As[kk][ty << 2];
      const float4 bv = *(const float4*)&Bs[kk][tx << 2];
      const float a[4] = {av.x, av.y, av.z, av.w};
      const float b[4] = {bv.x, bv.y, bv.z, bv.w};
#pragma unroll
      for (int i = 0; i < 4; ++i)
#pragma unroll
        for (int j = 0; j < 4; ++j) acc[i][j] = fmaf(a[i], b[j], acc[i][j]);
    }
  };

  // 2-deep ping-pong: slot A = even tiles, slot B = odd tiles; each slot
  // reloaded 2 tiles ahead -> ~2 FMA blocks of load window.
  float4 aA = loadA(kBeg), bA = loadB(kBeg);
  float4 aB = aA, bB = bA;  // init only; unused unless >=2 tiles
  if (kBeg + 16 < kEnd) { aB = loadA(kBeg + 16); bB = loadB(kBeg + 16); }
  for (int kt = kBeg; kt < kEnd; kt += 32) {
    __syncthreads();
    stAB(aA, bA);
    __syncthreads();
    if (kt + 32 < kEnd) { aA = loadA(kt + 32); bA = loadB(kt + 32); }
    domath();
    if (kt + 16 < kEnd) {
      __syncthreads();
      stAB(aB, bB);
      __syncthreads();
      if (kt + 48 < kEnd) { aB = loadA(kt + 48); bB = loadB(kt + 48); }
      domath();
    }
  }

#pragma unroll
  for (int i = 0; i < 4; ++i) {
    const int m = m0 + (ty << 2) + i;
    const int n = n0 + (tx << 2);
    float o[4] = {acc[i][0], acc[i][1], acc[i][2], acc[i][3]};
    if (OBIAS) {
#pragma unroll
      for (int j = 0; j < 4; ++j) o[j] += oBias[n + j];
    }
    if (ORES) {
      const float4 r4 = *(const float4*)(resz + (size_t)m * N + n);
      o[0] += r4.x; o[1] += r4.y; o[2] += r4.z; o[3] += r4.w;
    }
    stcc4(&Cb[(size_t)m * N + n], o[0], o[1], o[2], o[3]);
  }
}

// Reduce NPART QK partials row r (cols 0..127=Q, 128..255=K) into Qd + KT.
DEV void qksum_task(int r, const float* __restrict__ QKp,
                    float* __restrict__ Qd, float* __restrict__ KT) {
  const int tid = threadIdx.x;
  const int b = r >> 8, j = r & 255;
  const size_t off = (size_t)r * 256 + tid;
  float v = 0.0f;
#pragma unroll
  for (int p = 0; p < NPART; ++p) v += QKp[(long)p * QK_PS + off];
  if (tid < 128) {
    stcc(Qd + (size_t)r * 128 + tid, v);
  } else {
    stcc(KT + (size_t)b * 32768 + (size_t)(tid - 128) * 256 + j, v);
  }
}

// Dense H: row pair rp -> H[2rp..2rp+1][0..127] = relu(sum Hp + b1).
// Same p-ascending summation order as the old AFUSE path (bit-identical).
DEV void hsum_task(int rp, const float* __restrict__ Hp,
                   const float* __restrict__ b1, float* __restrict__ Hd) {
  const int tid = threadIdx.x;
  const int r = (rp << 1) | (tid >> 7), c = tid & 127;
  const size_t off = (size_t)r * HID + c;
  float v = 0.0f;
#pragma unroll
  for (int p = 0; p < NPART; ++p) v += Hp[(long)p * H_PS + off];
  stcc(Hd + off, fmaxf(v + b1[c], 0.0f));
}

// Scores + softmax for 2 q-rows. t in [0,512): b = t>>7, i0 = (t&127)*2.
// Arena: qs[0..255], wvs[256..383], red[384..387].
DEV void scores_task(float* smem, int t, const float* __restrict__ Qd,
                     const float* __restrict__ KT,
                     const float* __restrict__ wv,
                     float* __restrict__ attn) {
  const int b = t >> 7, i0 = (t & 127) << 1, tid = threadIdx.x;
  float (*qs)[128] = (float (*)[128])smem;
  float* wvs = smem + 256;
  float* red = smem + 384;
  {
    const int rr = tid >> 7, h = tid & 127;
    qs[rr][h] = Qd[(size_t)(b * 256 + i0 + rr) * 128 + h];
  }
  if (tid < 128) wvs[tid] = wv[tid];
  __syncthreads();

  const float* KTb = KT + (size_t)b * 32768 + tid;
  float s0 = 0.0f, s1 = 0.0f;
#pragma unroll 4
  for (int h = 0; h < 128; h += 4) {
    const float k0 = KTb[(h + 0) * 256];
    const float k1 = KTb[(h + 1) * 256];
    const float k2 = KTb[(h + 2) * 256];
    const float k3 = KTb[(h + 3) * 256];
    const float w0 = wvs[h], w1 = wvs[h + 1], w2 = wvs[h + 2], w3 = wvs[h + 3];
    s0 += w0 * ftanh(qs[0][h] + k0) + w1 * ftanh(qs[0][h + 1] + k1) +
          w2 * ftanh(qs[0][h + 2] + k2) + w3 * ftanh(qs[0][h + 3] + k3);
    s1 += w0 * ftanh(qs[1][h] + k0) + w1 * ftanh(qs[1][h + 1] + k1) +
          w2 * ftanh(qs[1][h + 2] + k2) + w3 * ftanh(qs[1][h + 3] + k3);
  }
  {
    const float mx = blockMax(s0, red);
    const float e = __expf(s0 - mx);
    const float tot = blockSum(e, red);
    stcc(attn + (size_t)(b * 256 + i0) * 256 + tid, e / tot);
  }
  {
    const float mx = blockMax(s1, red);
    const float e = __expf(s1 - mx);
    const float tot = blockSum(e, red);
    stcc(attn + (size_t)(b * 256 + i0 + 1) * 256 + tid, e / tot);
  }
}

// LayerNorm of row r of A -> Y (16B bypass stores via LDS staging).
// Arena: xbuf[0..1279], red[1280..1283].
DEV void ln_task(float* smem, int r, const float* __restrict__ A,
                 float* __restrict__ Y) {
  float* xbuf = smem;
  float* red = smem + 1280;
  const int tid = threadIdx.x;
  const float* a = A + (size_t)r * VEC;
  float v[5];
  float sum = 0.0f;
#pragma unroll
  for (int k = 0; k < 5; ++k) {
    v[k] = a[tid + k * 256];
    sum += v[k];
  }
  sum = blockSum(sum, red);
  const float m = sum * (1.0f / VEC);
  float sq = 0.0f;
#pragma unroll
  for (int k = 0; k < 5; ++k) {
    const float dl = v[k] - m;
    sq += dl * dl;
  }
  sq = blockSum(sq, red);
  const float rstd = rsqrtf(sq * (1.0f / VEC) + 1e-5f);
#pragma unroll
  for (int k = 0; k < 5; ++k) xbuf[tid + k * 256] = (v[k] - m) * rstd;
  __syncthreads();
  float* y = Y + (size_t)r * VEC;
  {
    const float* x = xbuf + (tid << 2);
    stcc4(y + (tid << 2), x[0], x[1], x[2], x[3]);
  }
  if (tid < 64) {
    const float* x = xbuf + 1024 + (tid << 2);
    stcc4(y + 1024 + (tid << 2), x[0], x[1], x[2], x[3]);
  }
  __syncthreads();  // xbuf reused by second ln_task call
}

// Fused layer-4 tail for batch b. Arena: qs 0-127, wvs 128-255, red 256-259,
// aws 260-515, xrow 516-1795, partial 1796-2051, h1s 2052-2083, h2s 2084-2095.
DEV void tail_task(float* smem, int b, const Params& p) {
  float* qs = smem;
  float* wvs = smem + 128;
  float* red = smem + 256;
  float* aws = smem + 260;
  float* xrow = smem + 516;
  float* partial = smem + 1796;
  float* h1s = smem + 2052;
  float* h2s = smem + 2084;
  const int tid = threadIdx.x;
  const int lp = p.lys[0];
  const float* X3 = p.Xout[2];
  const float* Qd = p.Qd[3];
  const float* KT = p.KT[3];

  if (tid < 128) {
    qs[tid] = Qd[(size_t)(b * 256 + lp) * 128 + tid];
    wvs[tid] = p.wv[3][tid];
  }
  __syncthreads();
  const float* KTb = KT + (size_t)b * 32768 + tid;
  float s = 0.0f;
#pragma unroll 4
  for (int h = 0; h < 128; h += 4) {
    s += wvs[h + 0] * ftanh(qs[h + 0] + KTb[(h + 0) * 256]);
    s += wvs[h + 1] * ftanh(qs[h + 1] + KTb[(h + 1) * 256]);
    s += wvs[h + 2] * ftanh(qs[h + 2] + KTb[(h + 2) * 256]);
    s += wvs[h + 3] * ftanh(qs[h + 3] + KTb[(h + 3) * 256]);
  }
  const float mx = blockMax(s, red);
  const float e = __expf(s - mx);
  const float tot = blockSum(e, red);
  aws[tid] = e / tot;
  __syncthreads();

  const float* Xb = X3 + (size_t)b * SS * VEC;
  float v[5] = {};
#pragma unroll 2
  for (int j = 0; j < 256; ++j) {
    const float aw = aws[j];
    const float* xr = Xb + (size_t)j * VEC + tid;
#pragma unroll
    for (int k = 0; k < 5; ++k) v[k] = fmaf(aw, xr[k * 256], v[k]);
  }
#pragma unroll
  for (int k = 0; k < 5; ++k) v[k] += Xb[(size_t)lp * VEC + tid + k * 256];

  float sum = (v[0] + v[1]) + (v[2] + v[3]) + v[4];
  sum = blockSum(sum, red);
  const float m = sum * (1.0f / VEC);
  float sq = 0.0f;
#pragma unroll
  for (int k = 0; k < 5; ++k) {
    const float dl = v[k] - m;
    sq += dl * dl;
  }
  sq = blockSum(sq, red);
  const float rstd = rsqrtf(sq * (1.0f / VEC) + 1e-5f);
#pragma unroll
  for (int k = 0; k < 5; ++k) xrow[tid + k * 256] = (v[k] - m) * rstd;
  __syncthreads();

  {
    const int n = tid & 31, sl = tid >> 5;
    float pacc = 0.0f;
    for (int k = sl * 160; k < sl * 160 + 160; ++k)
      pacc = fmaf(xrow[k], p.hW1[(size_t)k * 32 + n], pacc);
    partial[tid] = pacc;
  }
  __syncthreads();
  if (tid < 32) {
    float t2 = 0.0f;
#pragma unroll
    for (int s2 = 0; s2 < 8; ++s2) t2 += partial[s2 * 32 + tid];
    h1s[tid] = fmaxf(t2 + p.hb1[tid], 0.0f);
  }
  __syncthreads();
  if (tid < 12) {
    float t2 = 0.0f;
#pragma unroll
    for (int k = 0; k < 32; ++k) t2 = fmaf(h1s[k], p.hW2[k * 12 + tid], t2);
    h2s[tid] = fmaxf(t2 + p.hb2[tid], 0.0f);
  }
  __syncthreads();
  if (tid < 2) {
    float t2 = 0.0f;
#pragma unroll
    for (int k = 0; k < 12; ++k) t2 = fmaf(h2s[k], p.hW3[k * 2 + tid], t2);
    p.out[b * 2 + tid] = t2 + p.hb3[tid];  // normal store: kernel-end release
  }
}

// ---------------------------------------------------------------------------
// Persistent kernel: 768 blocks x 256 threads, launch_bounds(256,4) ->
// VGPR cap 128 (r9's measured use) -> HW capacity 4 blocks/CU; grid needs
// only 3/CU -> 256 slots slack (no exact-fit deadlock). LDS arena 8.7KB.
// ---------------------------------------------------------------------------
__global__ __launch_bounds__(256, 4) void mega_k(Params p) {
  __shared__ float smem[ARENA_F];
  const int bid = blockIdx.x;
  unsigned ph = 0;

  for (int l = 0; l < 4; ++l) {
    const float* Xin = (l == 0) ? p.X : p.Xout[l - 1];
    // QK projection: 4n x 16m x 8z = 512 tasks (<=1 per block).
    if (bid < 512) {
      const int x = bid & 3, y = (bid >> 2) & 15, z = bid >> 6;
      gemm_task<1, false, false>(smem, x * 64, y * 64, z, Xin, 0L,
          p.Wq[l], p.Wk[l], HID, 0L, HID, p.QKp[l], QK_PS,
          nullptr, nullptr, 2 * HID, VEC, 160);
    }
    gsync(p.bar, ++ph);
    // Reduce partials -> Qd + KT. 1024 rows; bid + extra 256.
    qksum_task(bid, p.QKp[l], p.Qd[l], p.KT[l]);
    if (bid < 256) qksum_task(bid + NBLK, p.QKp[l], p.Qd[l], p.KT[l]);
    gsync(p.bar, ++ph);
    if (l == 3) break;
    // Scores+softmax: 512 tasks (2 q-rows each).
    if (bid < 512) scores_task(smem, bid, p.Qd[l], p.KT[l], p.wv[l], p.attn[l]);
    gsync(p.bar, ++ph);
    // PV: attn @ Xin + Xin (batched). 20n x 4m x 4b = 320 tasks.
    if (bid < 320) {
      const int x = bid % 20, y = (bid / 20) & 3, zb = bid / 80;
      gemm_task<2, false, true>(smem, x * 64, y * 64, zb, p.attn[l],
          (long)SS * SS, Xin, Xin, NSPLIT_NONE, (long)SS * VEC, VEC,
          p.Yraw[l], (long)SS * VEC, nullptr, Xin, VEC, SS, 0);
    }
    gsync(p.bar, ++ph);
    // LN: 1024 rows; bid + extra 256.
    ln_task(smem, bid, p.Yraw[l], p.Yb[l]);
    if (bid < 256) ln_task(smem, bid + NBLK, p.Yraw[l], p.Yb[l]);
    gsync(p.bar, ++ph);
    // FC1: Yb @ rW1 -> Hp. 2n x 16m x 8z = 256 tasks.
    if (bid < 256) {
      const int x = bid & 1, y = (bid >> 1) & 15, z = bid >> 5;
      gemm_task<1, false, false>(smem, x * 64, y * 64, z, p.Yb[l], 0L,
          p.rW1[l], p.rW1[l], NSPLIT_NONE, 0L, HID, p.Hp[l], H_PS,
          nullptr, nullptr, HID, VEC, 160);
    }
    gsync(p.bar, ++ph);
    // Dense H = relu(sum Hp + b1): 512 row-pair tasks.
    if (bid < 512) hsum_task(bid, p.Hp[l], p.rb1[l], p.Hd[l]);
    gsync(p.bar, ++ph);
    // FC2: H @ rW2 + b2 + Yb. Plain GEMM, 20n x 16m = 320 tasks.
    if (bid < 320) {
      const int x = bid % 20, y = bid / 20;
      gemm_task<0, true, true>(smem, x * 64, y * 64, 0, p.Hd[l], 0L,
          p.rW2[l], p.rW2[l], NSPLIT_NONE, 0L, VEC, p.Xout[l], 0L,
          p.rb2[l], p.Yb[l], VEC, HID, 0);
    }
    gsync(p.bar, ++ph);
  }
  // Layer-4 tail: one block per batch, fully fused.
  if (bid < BB) tail_task(smem, bid, p);
}

__global__ void initbar_k(unsigned* __restrict__ bar) {
  const int tid = threadIdx.x;
  for (int i = tid; i < 1024; i += 256)
    __hip_atomic_store(bar + i, 0u, __ATOMIC_RELAXED,
                       __HIP_MEMORY_SCOPE_AGENT);
}

// ---------------------------------------------------------------------------
extern "C" void kernel_launch(void* const* d_in, const int* in_sizes, int n_in,
                              void* d_out, int out_size, void* d_ws, size_t ws_size,
                              hipStream_t stream) {
  Params p;
  p.X   = (const float*)d_in[0];
  p.lys = (const int*)d_in[1];
  p.Wq[0] = (const float*)d_in[2];  p.Wk[0] = (const float*)d_in[3];  p.wv[0] = (const float*)d_in[4];
  p.Wq[1] = (const float*)d_in[5];  p.Wk[1] = (const float*)d_in[6];  p.wv[1] = (const float*)d_in[7];
  p.Wq[2] = (const float*)d_in[8];  p.Wk[2] = (const float*)d_in[9];  p.wv[2] = (const float*)d_in[10];
  p.Wq[3] = (const float*)d_in[11]; p.Wk[3] = (const float*)d_in[12]; p.wv[3] = (const float*)d_in[13];
  p.rW1[0] = (const float*)d_in[14]; p.rb1[0] = (const float*)d_in[15];
  p.rW2[0] = (const float*)d_in[16]; p.rb2[0] = (const float*)d_in[17];
  p.rW1[1] = (const float*)d_in[18]; p.rb1[1] = (const float*)d_in[19];
  p.rW2[1] = (const float*)d_in[20]; p.rb2[1] = (const float*)d_in[21];
  p.rW1[2] = (const float*)d_in[22]; p.rb1[2] = (const float*)d_in[23];
  p.rW2[2] = (const float*)d_in[24]; p.rb2[2] = (const float*)d_in[25];
  p.hW1 = (const float*)d_in[26]; p.hb1 = (const float*)d_in[27];
  p.hW2 = (const float*)d_in[28]; p.hb2 = (const float*)d_in[29];
  p.hW3 = (const float*)d_in[30]; p.hb3 = (const float*)d_in[31];
  p.out = (float*)d_out;

  // Write-once versioned workspace (floats), ~99 MB (4KB-aligned buffers).
  float* w = (float*)d_ws;
  for (int l = 0; l < 4; ++l) { p.QKp[l] = w; w += (long)NPART * QK_PS; }  // 4 x 8MB
  for (int l = 0; l < 4; ++l) { p.Qd[l]  = w; w += 131072; }               // 4 x 0.5MB
  for (int l = 0; l < 4; ++l) { p.KT[l]  = w; w += 131072; }               // 4 x 0.5MB
  for (int l = 0; l < 3; ++l) { p.attn[l] = w; w += 262144; }              // 3 x 1MB
  for (int l = 0; l < 3; ++l) { p.Yraw[l] = w; w += 1310720; }             // 3 x 5MB
  for (int l = 0; l < 3; ++l) { p.Yb[l]   = w; w += 1310720; }             // 3 x 5MB
  for (int l = 0; l < 3; ++l) { p.Hp[l]   = w; w += (long)NPART * H_PS; }  // 3 x 4MB
  for (int l = 0; l < 3; ++l) { p.Hd[l]   = w; w += 131072; }              // 3 x 0.5MB
  for (int l = 0; l < 3; ++l) { p.Xout[l] = w; w += 1310720; }             // 3 x 5MB
  p.bar = (unsigned*)w;                                                    // 1024 u32

  initbar_k<<<dim3(1), dim3(256), 0, stream>>>(p.bar);
  mega_k<<<dim3(NBLK), dim3(256), 0, stream>>>(p);
}

// Round 9
// 522.562 us; speedup vs baseline: 1.4761x; 1.4761x over previous
//
#include <hip/hip_runtime.h>

// AttentionBasedNN: persistent mega-kernel, round-13.
// VEC=1280, HID=128, B=4, S=256, fp32 (no fp32 MFMA on CDNA4 -> vector ALU).
//
// Coherence scheme (proven rounds 6-11): intermediates are WRITE-ONCE
// versioned buffers; stores bypass L1/L2 (sc0 sc1 -> coherence point),
// loads normal cached; grid barrier = fence-free monotonic tree counters.
//
// Round-12 post-mortem: harness died with a Trio-nursery infra error (no
// kernel signature; prior rounds show the push path flaking). Per the
// one-variable rule, round-13 = r9 skeleton VERBATIM (430us proven, grid
// 512, launch_bounds(256,2)) + exactly ONE change:
//   Dense-H: hsum phase materializes H = relu(sum Hp + b1) once
//   (p-ascending order -> bit-identical); FC2 becomes a plain K=128 GEMM.
//   Kills FC2's 8-way partial re-read (~240MB of issued loads across the
//   3 layers, which also blocked the 2-deep prefetch in the AFUSE path).

#define DEV __device__ __forceinline__

static constexpr int VEC = 1280;
static constexpr int HID = 128;
static constexpr int BB  = 4;
static constexpr int SS  = 256;
static constexpr int NPART = 8;           // split-K partials (QK and FC1)
static constexpr long QK_PS = 262144;     // QK partial stride (1024*256)
static constexpr long H_PS  = 131072;     // FC1 partial stride (1024*128)
static constexpr int NBLK  = 512;         // persistent grid: 2 blocks/CU
static constexpr int NSPLIT_NONE = 1 << 30;

typedef float f32x4 __attribute__((ext_vector_type(4)));

struct Params {
  const float* X; const int* lys;
  const float* Wq[4]; const float* Wk[4]; const float* wv[4];
  const float* rW1[3]; const float* rb1[3]; const float* rW2[3]; const float* rb2[3];
  const float* hW1; const float* hb1; const float* hW2; const float* hb2;
  const float* hW3; const float* hb3;
  float* QKp[4]; float* Qd[4]; float* KT[4];   // per attention layer
  float* attn[3]; float* Yraw[3]; float* Yb[3];
  float* Hp[3]; float* Hd[3]; float* Xout[3];
  float* out;
  // bar layout (u32): [0..255] 8 group arrive ctrs (stride 32); [256] root;
  // [288] gen. (r9-proven layout.)
  unsigned* bar;
};

// ---- bypass stores (agent-scope, straight to coherence point) -------------
DEV void stcc(float* p, float v) {
  union { float f; unsigned u; } c; c.f = v;
  __hip_atomic_store((unsigned*)p, c.u, __ATOMIC_RELAXED,
                     __HIP_MEMORY_SCOPE_AGENT);
}
DEV void stcc4(float* p, float x, float y, float z, float w) {
  f32x4 v; v[0] = x; v[1] = y; v[2] = z; v[3] = w;
  asm volatile("global_store_dwordx4 %0, %1, off sc0 sc1"
               :: "v"(p), "v"(v) : "memory");
}

DEV float ftanh(float x) {
  float e = __expf(2.0f * x);
  return 1.0f - __fdividef(2.0f, e + 1.0f);
}

DEV float waveSum(float v) {
#pragma unroll
  for (int off = 32; off > 0; off >>= 1) v += __shfl_xor(v, off, 64);
  return v;
}
DEV float waveMax(float v) {
#pragma unroll
  for (int off = 32; off > 0; off >>= 1) v = fmaxf(v, __shfl_xor(v, off, 64));
  return v;
}
// blockDim.x == 256 (4 waves) everywhere these are used.
DEV float blockSum(float v, float* red) {
  v = waveSum(v);
  int tid = threadIdx.x;
  if ((tid & 63) == 0) red[tid >> 6] = v;
  __syncthreads();
  float r = (red[0] + red[1]) + (red[2] + red[3]);
  __syncthreads();
  return r;
}
DEV float blockMax(float v, float* red) {
  v = waveMax(v);
  int tid = threadIdx.x;
  if ((tid & 63) == 0) red[tid >> 6] = v;
  __syncthreads();
  float r = fmaxf(fmaxf(red[0], red[1]), fmaxf(red[2], red[3]));
  __syncthreads();
  return r;
}

// Fence-free grid barrier (r9-proven verbatim). 8 groups of 64 blocks.
DEV void gsync(unsigned* bar, unsigned target) {
  __syncthreads();  // each wave drains its own vmcnt before s_barrier
  if (threadIdx.x == 0) {
    asm volatile("s_waitcnt vmcnt(0)" ::: "memory");
    unsigned* grp  = bar + ((blockIdx.x >> 6) << 5);
    unsigned* root = bar + 256;
    unsigned* gen  = bar + 288;
    unsigned c = __hip_atomic_fetch_add(grp, 1u, __ATOMIC_RELAXED,
                                        __HIP_MEMORY_SCOPE_AGENT);
    if (c + 1u == target * 64u) {
      unsigned r = __hip_atomic_fetch_add(root, 1u, __ATOMIC_RELAXED,
                                          __HIP_MEMORY_SCOPE_AGENT);
      if (r + 1u == target * 8u) {
        __hip_atomic_store(gen, target, __ATOMIC_RELAXED,
                           __HIP_MEMORY_SCOPE_AGENT);
      }
    }
    while (__hip_atomic_load(gen, __ATOMIC_RELAXED,
                             __HIP_MEMORY_SCOPE_AGENT) < target)
      __builtin_amdgcn_s_sleep(2);
  }
  __syncthreads();
}

// ---------------------------------------------------------------------------
// fp32 GEMM task, 64x64 tile, BK=16, 256 threads, 4x4 microtile, 2-deep
// ping-pong register prefetch (r9 proven; FMA order unchanged). No AFUSE
// path anymore (Dense-H made it unnecessary).
// MODE==0: plain.  MODE==1: z = K-split slice (kChunk each), C += z*sCb.
// MODE==2: z = batch; A += z*sAb, B += z*sBb, C/res += z*sCb.
// Loads cached (write-once buffers); C-stores bypass 16B.
// ---------------------------------------------------------------------------
template <int MODE, bool OBIAS, bool ORES>
DEV void gemm_task(int n0, int m0, int z,
                   const float* __restrict__ A, long sAb,
                   const float* __restrict__ B0, const float* __restrict__ B1,
                   int nSplitB, long sBb, int ldB,
                   float* __restrict__ C, long sCb,
                   const float* __restrict__ oBias,
                   const float* __restrict__ res,
                   int N, int K, int kChunk) {
  __shared__ float As[16][68];  // [k][m]
  __shared__ float Bs[16][68];  // [k][n]

  const float* Ab = A + (MODE == 2 ? (long)z * sAb : 0L);
  float*       Cb = C + (MODE >= 1 ? (long)z * sCb : 0L);
  const float* resz = ORES ? (res + (MODE == 2 ? (long)z * sCb : 0L)) : nullptr;
  const float* Bsel;
  int nb;
  if (n0 < nSplitB) { Bsel = B0; nb = n0; } else { Bsel = B1; nb = n0 - nSplitB; }
  if (MODE == 2) Bsel += (long)z * sBb;

  const int kBeg = (MODE == 1) ? z * kChunk : 0;
  const int kEnd = (MODE == 1) ? kBeg + kChunk : K;

  const int tid = threadIdx.x;
  const int tx = tid & 15, ty = tid >> 4;
  const int ar = tid >> 2, ac = (tid & 3) << 2;   // A: row 0..63, k {0,4,8,12}
  const int br = tid >> 4, bc = (tid & 15) << 2;  // B: k-row 0..15, col 0..60

  auto loadA = [&](int kt) -> float4 {
    return *(const float4*)(Ab + (size_t)(m0 + ar) * K + kt + ac);
  };
  auto loadB = [&](int kt) -> float4 {
    return *(const float4*)(Bsel + (size_t)(kt + br) * ldB + nb + bc);
  };
  auto stAB = [&](const float4& a4, const float4& b4) {
    As[ac + 0][ar] = a4.x;
    As[ac + 1][ar] = a4.y;
    As[ac + 2][ar] = a4.z;
    As[ac + 3][ar] = a4.w;
    *(float4*)&Bs[br][bc] = b4;
  };

  float acc[4][4] = {};
  auto domath = [&]() {
#pragma unroll
    for (int kk = 0; kk < 16; ++kk) {
      const float4 av = *(const float4*)&As[kk][ty << 2];
      const float4 bv = *(const float4*)&Bs[kk][tx << 2];
      const float a[4] = {av.x, av.y, av.z, av.w};
      const float b[4] = {bv.x, bv.y, bv.z, bv.w};
#pragma unroll
      for (int i = 0; i < 4; ++i)
#pragma unroll
        for (int j = 0; j < 4; ++j) acc[i][j] = fmaf(a[i], b[j], acc[i][j]);
    }
  };

  // 2-deep ping-pong: slot A = even tiles, slot B = odd tiles; each slot
  // reloaded 2 tiles ahead -> ~2 FMA blocks of load window.
  float4 aA = loadA(kBeg), bA = loadB(kBeg);
  float4 aB = aA, bB = bA;  // init only; unused unless >=2 tiles
  if (kBeg + 16 < kEnd) { aB = loadA(kBeg + 16); bB = loadB(kBeg + 16); }
  for (int kt = kBeg; kt < kEnd; kt += 32) {
    __syncthreads();
    stAB(aA, bA);
    __syncthreads();
    if (kt + 32 < kEnd) { aA = loadA(kt + 32); bA = loadB(kt + 32); }
    domath();
    if (kt + 16 < kEnd) {
      __syncthreads();
      stAB(aB, bB);
      __syncthreads();
      if (kt + 48 < kEnd) { aB = loadA(kt + 48); bB = loadB(kt + 48); }
      domath();
    }
  }

#pragma unroll
  for (int i = 0; i < 4; ++i) {
    const int m = m0 + (ty << 2) + i;
    const int n = n0 + (tx << 2);
    float o[4] = {acc[i][0], acc[i][1], acc[i][2], acc[i][3]};
    if (OBIAS) {
#pragma unroll
      for (int j = 0; j < 4; ++j) o[j] += oBias[n + j];
    }
    if (ORES) {
      const float4 r4 = *(const float4*)(resz + (size_t)m * N + n);
      o[0] += r4.x; o[1] += r4.y; o[2] += r4.z; o[3] += r4.w;
    }
    stcc4(&Cb[(size_t)m * N + n], o[0], o[1], o[2], o[3]);
  }
}

// Reduce NPART QK partials row r (cols 0..127=Q, 128..255=K) into Qd + KT.
DEV void qksum_task(int r, const float* __restrict__ QKp,
                    float* __restrict__ Qd, float* __restrict__ KT) {
  const int tid = threadIdx.x;
  const int b = r >> 8, j = r & 255;
  const size_t off = (size_t)r * 256 + tid;
  float v = 0.0f;
#pragma unroll
  for (int p = 0; p < NPART; ++p) v += QKp[(long)p * QK_PS + off];
  if (tid < 128) {
    stcc(Qd + (size_t)r * 128 + tid, v);
  } else {
    stcc(KT + (size_t)b * 32768 + (size_t)(tid - 128) * 256 + j, v);
  }
}

// Dense H: row pair rp -> Hd[2rp..2rp+1][0..127] = relu(sum Hp + b1).
// p-ascending summation order == old AFUSE path (bit-identical values).
DEV void hsum_task(int rp, const float* __restrict__ Hp,
                   const float* __restrict__ b1, float* __restrict__ Hd) {
  const int tid = threadIdx.x;
  const int r = (rp << 1) | (tid >> 7), c = tid & 127;
  const size_t off = (size_t)r * HID + c;
  float v = 0.0f;
#pragma unroll
  for (int p = 0; p < NPART; ++p) v += Hp[(long)p * H_PS + off];
  stcc(Hd + off, fmaxf(v + b1[c], 0.0f));
}

// Scores + softmax for 2 q-rows. t in [0,512): b = t>>7, i0 = (t&127)*2.
DEV void scores_task(int t, const float* __restrict__ Qd,
                     const float* __restrict__ KT,
                     const float* __restrict__ wv,
                     float* __restrict__ attn) {
  const int b = t >> 7, i0 = (t & 127) << 1, tid = threadIdx.x;
  __shared__ float qs[2][128], wvs[128], red[4];
  {
    const int rr = tid >> 7, h = tid & 127;
    qs[rr][h] = Qd[(size_t)(b * 256 + i0 + rr) * 128 + h];
  }
  if (tid < 128) wvs[tid] = wv[tid];
  __syncthreads();

  const float* KTb = KT + (size_t)b * 32768 + tid;
  float s0 = 0.0f, s1 = 0.0f;
#pragma unroll 4
  for (int h = 0; h < 128; h += 4) {
    const float k0 = KTb[(h + 0) * 256];
    const float k1 = KTb[(h + 1) * 256];
    const float k2 = KTb[(h + 2) * 256];
    const float k3 = KTb[(h + 3) * 256];
    const float w0 = wvs[h], w1 = wvs[h + 1], w2 = wvs[h + 2], w3 = wvs[h + 3];
    s0 += w0 * ftanh(qs[0][h] + k0) + w1 * ftanh(qs[0][h + 1] + k1) +
          w2 * ftanh(qs[0][h + 2] + k2) + w3 * ftanh(qs[0][h + 3] + k3);
    s1 += w0 * ftanh(qs[1][h] + k0) + w1 * ftanh(qs[1][h + 1] + k1) +
          w2 * ftanh(qs[1][h + 2] + k2) + w3 * ftanh(qs[1][h + 3] + k3);
  }
  {
    const float mx = blockMax(s0, red);
    const float e = __expf(s0 - mx);
    const float tot = blockSum(e, red);
    stcc(attn + (size_t)(b * 256 + i0) * 256 + tid, e / tot);
  }
  {
    const float mx = blockMax(s1, red);
    const float e = __expf(s1 - mx);
    const float tot = blockSum(e, red);
    stcc(attn + (size_t)(b * 256 + i0 + 1) * 256 + tid, e / tot);
  }
}

// LayerNorm of row r of A -> Y (16B bypass stores via LDS staging).
DEV void ln_task(int r, const float* __restrict__ A, float* __restrict__ Y) {
  __shared__ float red[4];
  __shared__ float xbuf[1280];
  const int tid = threadIdx.x;
  const float* a = A + (size_t)r * VEC;
  float v[5];
  float sum = 0.0f;
#pragma unroll
  for (int k = 0; k < 5; ++k) {
    v[k] = a[tid + k * 256];
    sum += v[k];
  }
  sum = blockSum(sum, red);
  const float m = sum * (1.0f / VEC);
  float sq = 0.0f;
#pragma unroll
  for (int k = 0; k < 5; ++k) {
    const float dl = v[k] - m;
    sq += dl * dl;
  }
  sq = blockSum(sq, red);
  const float rstd = rsqrtf(sq * (1.0f / VEC) + 1e-5f);
#pragma unroll
  for (int k = 0; k < 5; ++k) xbuf[tid + k * 256] = (v[k] - m) * rstd;
  __syncthreads();
  float* y = Y + (size_t)r * VEC;
  {
    const float* x = xbuf + (tid << 2);
    stcc4(y + (tid << 2), x[0], x[1], x[2], x[3]);
  }
  if (tid < 64) {
    const float* x = xbuf + 1024 + (tid << 2);
    stcc4(y + 1024 + (tid << 2), x[0], x[1], x[2], x[3]);
  }
  __syncthreads();  // xbuf reused by second ln_task call
}

// Fused layer-4 tail for batch b: scores4 + pv4 + LN + head, all in-block.
DEV void tail_task(int b, const Params& p) {
  __shared__ float qs[128], wvs[128], red[4], aws[256];
  __shared__ float xrow[1280], partial[256];
  __shared__ float h1s[32], h2s[12];
  const int tid = threadIdx.x;
  const int lp = p.lys[0];
  const float* X3 = p.Xout[2];
  const float* Qd = p.Qd[3];
  const float* KT = p.KT[3];

  if (tid < 128) {
    qs[tid] = Qd[(size_t)(b * 256 + lp) * 128 + tid];
    wvs[tid] = p.wv[3][tid];
  }
  __syncthreads();
  const float* KTb = KT + (size_t)b * 32768 + tid;
  float s = 0.0f;
#pragma unroll 4
  for (int h = 0; h < 128; h += 4) {
    s += wvs[h + 0] * ftanh(qs[h + 0] + KTb[(h + 0) * 256]);
    s += wvs[h + 1] * ftanh(qs[h + 1] + KTb[(h + 1) * 256]);
    s += wvs[h + 2] * ftanh(qs[h + 2] + KTb[(h + 2) * 256]);
    s += wvs[h + 3] * ftanh(qs[h + 3] + KTb[(h + 3) * 256]);
  }
  const float mx = blockMax(s, red);
  const float e = __expf(s - mx);
  const float tot = blockSum(e, red);
  aws[tid] = e / tot;
  __syncthreads();

  // PV: 5 cols per thread (coalesced rows of X3[b]).
  const float* Xb = X3 + (size_t)b * SS * VEC;
  float v[5] = {};
#pragma unroll 2
  for (int j = 0; j < 256; ++j) {
    const float aw = aws[j];
    const float* xr = Xb + (size_t)j * VEC + tid;
#pragma unroll
    for (int k = 0; k < 5; ++k) v[k] = fmaf(aw, xr[k * 256], v[k]);
  }
#pragma unroll
  for (int k = 0; k < 5; ++k) v[k] += Xb[(size_t)lp * VEC + tid + k * 256];

  // LN over the 1280-wide attended row.
  float sum = (v[0] + v[1]) + (v[2] + v[3]) + v[4];
  sum = blockSum(sum, red);
  const float m = sum * (1.0f / VEC);
  float sq = 0.0f;
#pragma unroll
  for (int k = 0; k < 5; ++k) {
    const float dl = v[k] - m;
    sq += dl * dl;
  }
  sq = blockSum(sq, red);
  const float rstd = rsqrtf(sq * (1.0f / VEC) + 1e-5f);
#pragma unroll
  for (int k = 0; k < 5; ++k) xrow[tid + k * 256] = (v[k] - m) * rstd;
  __syncthreads();

  // Head: 1280 -> 32 (relu) -> 12 (relu) -> 2.
  {
    const int n = tid & 31, sl = tid >> 5;
    float pacc = 0.0f;
    for (int k = sl * 160; k < sl * 160 + 160; ++k)
      pacc = fmaf(xrow[k], p.hW1[(size_t)k * 32 + n], pacc);
    partial[tid] = pacc;
  }
  __syncthreads();
  if (tid < 32) {
    float t2 = 0.0f;
#pragma unroll
    for (int s2 = 0; s2 < 8; ++s2) t2 += partial[s2 * 32 + tid];
    h1s[tid] = fmaxf(t2 + p.hb1[tid], 0.0f);
  }
  __syncthreads();
  if (tid < 12) {
    float t2 = 0.0f;
#pragma unroll
    for (int k = 0; k < 32; ++k) t2 = fmaf(h1s[k], p.hW2[k * 12 + tid], t2);
    h2s[tid] = fmaxf(t2 + p.hb2[tid], 0.0f);
  }
  __syncthreads();
  if (tid < 2) {
    float t2 = 0.0f;
#pragma unroll
    for (int k = 0; k < 12; ++k) t2 = fmaf(h2s[k], p.hW3[k * 2 + tid], t2);
    p.out[b * 2 + tid] = t2 + p.hb3[tid];  // normal store: kernel-end release
  }
}

// ---------------------------------------------------------------------------
// The persistent kernel. 512 blocks x 256 threads; __launch_bounds__(256,2)
// (r9-proven residency: LDS ~41KB -> capacity 3/CU > 2 requested).
// ---------------------------------------------------------------------------
__global__ __launch_bounds__(256, 2) void mega_k(Params p) {
  const int bid = blockIdx.x;
  unsigned ph = 0;

  for (int l = 0; l < 4; ++l) {
    const float* Xin = (l == 0) ? p.X : p.Xout[l - 1];
    {  // QK projection: 4n x 16m x 8z = 512 tasks.
      const int x = bid & 3, y = (bid >> 2) & 15, z = bid >> 6;
      gemm_task<1, false, false>(x * 64, y * 64, z, Xin, 0L,
          p.Wq[l], p.Wk[l], HID, 0L, HID, p.QKp[l], QK_PS,
          nullptr, nullptr, 2 * HID, VEC, 160);
    }
    gsync(p.bar, ++ph);
    // Reduce partials -> dense Qd + transposed KT. 1024 rows / 512 blocks.
    qksum_task(bid, p.QKp[l], p.Qd[l], p.KT[l]);
    qksum_task(bid + NBLK, p.QKp[l], p.Qd[l], p.KT[l]);
    gsync(p.bar, ++ph);
    if (l == 3) break;
    // attn = softmax(wv . tanh(q_i + k_j)). 512 tasks.
    scores_task(bid, p.Qd[l], p.KT[l], p.wv[l], p.attn[l]);
    gsync(p.bar, ++ph);
    // Yraw = attn @ Xin + Xin (batched). 320 tasks.
    if (bid < 320) {
      const int x = bid % 20, y = (bid / 20) & 3, zb = bid / 80;
      gemm_task<2, false, true>(x * 64, y * 64, zb, p.attn[l],
          (long)SS * SS, Xin, Xin, NSPLIT_NONE, (long)SS * VEC, VEC,
          p.Yraw[l], (long)SS * VEC, nullptr, Xin, VEC, SS, 0);
    }
    gsync(p.bar, ++ph);
    // Yb = LN(Yraw). 1024 rows / 512 blocks.
    ln_task(bid, p.Yraw[l], p.Yb[l]);
    ln_task(bid + NBLK, p.Yraw[l], p.Yb[l]);
    gsync(p.bar, ++ph);
    // FC1: Yb @ rW1 -> Hp. 2n x 16m x 8z = 256 tasks.
    if (bid < 256) {
      const int x = bid & 1, y = (bid >> 1) & 15, z = bid >> 5;
      gemm_task<1, false, false>(x * 64, y * 64, z, p.Yb[l], 0L,
          p.rW1[l], p.rW1[l], NSPLIT_NONE, 0L, HID, p.Hp[l], H_PS,
          nullptr, nullptr, HID, VEC, 160);
    }
    gsync(p.bar, ++ph);
    // Dense H = relu(sum Hp + b1): 512 row-pair tasks.
    hsum_task(bid, p.Hp[l], p.rb1[l], p.Hd[l]);
    gsync(p.bar, ++ph);
    // FC2: Hd @ rW2 + b2 + Yb. Plain GEMM (K=128), 20n x 16m = 320 tasks.
    if (bid < 320) {
      const int x = bid % 20, y = bid / 20;
      gemm_task<0, true, true>(x * 64, y * 64, 0, p.Hd[l], 0L,
          p.rW2[l], p.rW2[l], NSPLIT_NONE, 0L, VEC, p.Xout[l], 0L,
          p.rb2[l], p.Yb[l], VEC, HID, 0);
    }
    gsync(p.bar, ++ph);
  }
  // Layer-4 tail: one block per batch, fully fused.
  if (bid < BB) tail_task(bid, p);
}

__global__ void initbar_k(unsigned* __restrict__ bar) {
  const int tid = threadIdx.x;
  for (int i = tid; i < 512; i += 256)
    __hip_atomic_store(bar + i, 0u, __ATOMIC_RELAXED,
                       __HIP_MEMORY_SCOPE_AGENT);
}

// ---------------------------------------------------------------------------
extern "C" void kernel_launch(void* const* d_in, const int* in_sizes, int n_in,
                              void* d_out, int out_size, void* d_ws, size_t ws_size,
                              hipStream_t stream) {
  Params p;
  p.X   = (const float*)d_in[0];
  p.lys = (const int*)d_in[1];
  p.Wq[0] = (const float*)d_in[2];  p.Wk[0] = (const float*)d_in[3];  p.wv[0] = (const float*)d_in[4];
  p.Wq[1] = (const float*)d_in[5];  p.Wk[1] = (const float*)d_in[6];  p.wv[1] = (const float*)d_in[7];
  p.Wq[2] = (const float*)d_in[8];  p.Wk[2] = (const float*)d_in[9];  p.wv[2] = (const float*)d_in[10];
  p.Wq[3] = (const float*)d_in[11]; p.Wk[3] = (const float*)d_in[12]; p.wv[3] = (const float*)d_in[13];
  p.rW1[0] = (const float*)d_in[14]; p.rb1[0] = (const float*)d_in[15];
  p.rW2[0] = (const float*)d_in[16]; p.rb2[0] = (const float*)d_in[17];
  p.rW1[1] = (const float*)d_in[18]; p.rb1[1] = (const float*)d_in[19];
  p.rW2[1] = (const float*)d_in[20]; p.rb2[1] = (const float*)d_in[21];
  p.rW1[2] = (const float*)d_in[22]; p.rb1[2] = (const float*)d_in[23];
  p.rW2[2] = (const float*)d_in[24]; p.rb2[2] = (const float*)d_in[25];
  p.hW1 = (const float*)d_in[26]; p.hb1 = (const float*)d_in[27];
  p.hW2 = (const float*)d_in[28]; p.hb2 = (const float*)d_in[29];
  p.hW3 = (const float*)d_in[30]; p.hb3 = (const float*)d_in[31];
  p.out = (float*)d_out;

  // Write-once versioned workspace (floats), ~101 MB (4KB-aligned buffers).
  float* w = (float*)d_ws;
  for (int l = 0; l < 4; ++l) { p.QKp[l] = w; w += (long)NPART * QK_PS; }  // 4 x 8MB
  for (int l = 0; l < 4; ++l) { p.Qd[l]  = w; w += 131072; }               // 4 x 0.5MB
  for (int l = 0; l < 4; ++l) { p.KT[l]  = w; w += 131072; }               // 4 x 0.5MB
  for (int l = 0; l < 3; ++l) { p.attn[l] = w; w += 262144; }              // 3 x 1MB
  for (int l = 0; l < 3; ++l) { p.Yraw[l] = w; w += 1310720; }             // 3 x 5MB
  for (int l = 0; l < 3; ++l) { p.Yb[l]   = w; w += 1310720; }             // 3 x 5MB
  for (int l = 0; l < 3; ++l) { p.Hp[l]   = w; w += (long)NPART * H_PS; }  // 3 x 4MB
  for (int l = 0; l < 3; ++l) { p.Hd[l]   = w; w += 131072; }              // 3 x 0.5MB
  for (int l = 0; l < 3; ++l) { p.Xout[l] = w; w += 1310720; }             // 3 x 5MB
  p.bar = (unsigned*)w;                                                    // 512 u32

  initbar_k<<<dim3(1), dim3(256), 0, stream>>>(p.bar);
  mega_k<<<dim3(NBLK), dim3(256), 0, stream>>>(p);
}